// Round 1
// baseline (206.650 us; speedup 1.0000x reference)
//
#include <hip/hip_runtime.h>
#include <hip/hip_bf16.h>

#define NB 16
#define NT 2048
#define NC 256
#define NM (NB*NT)          // 32768 rows
#define NCH 16              // cumsum chunks
#define NCL (NT/NCH)        // 128 per chunk

typedef __attribute__((ext_vector_type(8))) short short8;
typedef __attribute__((ext_vector_type(4))) float f32x4;

__device__ __forceinline__ unsigned short f2bf(float x){
    union { float f; unsigned u; } v; v.f = x;
    unsigned r = v.u + 0x7FFFu + ((v.u >> 16) & 1u);   // RNE
    return (unsigned short)(r >> 16);
}

// ---- prep: bf16 time_w table (zero-padded to 4096) + transposed bf16 weights ----
__global__ void prep_kernel(const float* __restrict__ tw,
                            const float* __restrict__ Wk, const float* __restrict__ Wv,
                            const float* __restrict__ Wr, const float* __restrict__ Wo,
                            unsigned short* __restrict__ twb,
                            unsigned short* __restrict__ WkT, unsigned short* __restrict__ WvT,
                            unsigned short* __restrict__ WrT, unsigned short* __restrict__ WoT){
    int gid = blockIdx.x*256 + threadIdx.x;          // 65536 threads
    if (gid < 4096) twb[gid] = (gid < NT) ? f2bf(tw[gid]) : (unsigned short)0;
    int n = gid >> 8, c = gid & 255;
    int src = c*NC + n;                               // W[c][n] -> WT[n][c]
    WkT[gid] = f2bf(Wk[src]);
    WvT[gid] = f2bf(Wv[src]);
    WrT[gid] = f2bf(Wr[src]);
    WoT[gid] = f2bf(Wo[src]);
}

// ---- time-shift mix -> xk/xv/xr (bf16) ----
__global__ void mix_kernel(const float* __restrict__ x,
                           const float* __restrict__ tmk, const float* __restrict__ tmv,
                           const float* __restrict__ tmr,
                           unsigned short* __restrict__ xk, unsigned short* __restrict__ xv,
                           unsigned short* __restrict__ xr){
    int gid = blockIdx.x*256 + threadIdx.x;           // NM*NC/8
    int m = gid >> 5;
    int c0 = (gid & 31) << 3;
    int t = m & (NT-1);
    size_t base = (size_t)m*NC + c0;
    float xa[8], xb[8];
    #pragma unroll
    for (int j=0;j<8;j+=4) *(float4*)&xa[j] = *(const float4*)&x[base+j];
    if (t > 0) {
        #pragma unroll
        for (int j=0;j<8;j+=4) *(float4*)&xb[j] = *(const float4*)&x[base - NC + j];
    } else {
        #pragma unroll
        for (int j=0;j<8;j++) xb[j]=0.f;
    }
    short8 ok, ov, orr;
    #pragma unroll
    for (int j=0;j<8;j++){
        float mk = tmk[c0+j], mv = tmv[c0+j], mr = tmr[c0+j];
        ok[j]  = (short)f2bf(xa[j]*mk + xb[j]*(1.f-mk));
        ov[j]  = (short)f2bf(xa[j]*mv + xb[j]*(1.f-mv));
        orr[j] = (short)f2bf(xa[j]*mr + xb[j]*(1.f-mr));
    }
    *(short8*)&xk[base] = ok;
    *(short8*)&xv[base] = ov;
    *(short8*)&xr[base] = orr;
}

// ---- generic [M,256]@[256,256] bf16 MFMA GEMM, f32 out with epilogue ----
// A row-major [M,256]; BT = B^T row-major [256,256] (k contiguous per n-row).
// MODE 0: plain, 1: exp(clip(.,-60,30)), 2: sigmoid
template<int MODE>
__global__ __launch_bounds__(256) void gemm_c(const unsigned short* __restrict__ A,
                                              const unsigned short* __restrict__ BT,
                                              float* __restrict__ Cout){
    __shared__ unsigned short As[64][40];   // +8 pad: 80B stride, 2-way max (free)
    __shared__ unsigned short Bs[64][40];
    const int tid = threadIdx.x;
    const int lane = tid & 63, w = tid >> 6;
    const int wm = (w >> 1) * 32, wn = (w & 1) * 32;
    const int r = tid >> 2, kk = (tid & 3) << 3;
    const int m_base = blockIdx.x * 64, n_base = blockIdx.y * 64;
    const int lrow = lane & 15, krow = (lane >> 4) << 3;
    f32x4 acc[2][2] = {};
    for (int k0 = 0; k0 < NC; k0 += 32) {
        *(short8*)&As[r][kk] = *(const short8*)&A[(size_t)(m_base + r)*NC + k0 + kk];
        *(short8*)&Bs[r][kk] = *(const short8*)&BT[(size_t)(n_base + r)*NC + k0 + kk];
        __syncthreads();
        short8 a0 = *(const short8*)&As[wm + lrow][krow];
        short8 a1 = *(const short8*)&As[wm + 16 + lrow][krow];
        short8 b0 = *(const short8*)&Bs[wn + lrow][krow];
        short8 b1 = *(const short8*)&Bs[wn + 16 + lrow][krow];
        acc[0][0] = __builtin_amdgcn_mfma_f32_16x16x32_bf16(a0,b0,acc[0][0],0,0,0);
        acc[0][1] = __builtin_amdgcn_mfma_f32_16x16x32_bf16(a0,b1,acc[0][1],0,0,0);
        acc[1][0] = __builtin_amdgcn_mfma_f32_16x16x32_bf16(a1,b0,acc[1][0],0,0,0);
        acc[1][1] = __builtin_amdgcn_mfma_f32_16x16x32_bf16(a1,b1,acc[1][1],0,0,0);
        __syncthreads();
    }
    const int orow = m_base + wm + ((lane >> 4) << 2);
    const int ocol = n_base + wn + lrow;
    #pragma unroll
    for (int mi=0;mi<2;mi++)
    #pragma unroll
    for (int ni=0;ni<2;ni++)
    #pragma unroll
    for (int i=0;i<4;i++){
        float vv = acc[mi][ni][i];
        if (MODE==1) vv = __expf(fminf(fmaxf(vv,-60.f),30.f));
        if (MODE==2) vv = 1.f/(1.f+__expf(-vv));
        Cout[(size_t)(orow + mi*16 + i)*NC + ocol + ni*16] = vv;
    }
}

// ---- kv = k*v, stored transposed [B][C][T] (bf16) via LDS tile transpose ----
__global__ __launch_bounds__(256) void kv_kernel(const float* __restrict__ kf,
                                                 const float* __restrict__ vf,
                                                 unsigned short* __restrict__ kvt){
    __shared__ unsigned short tile[64][65];
    const int tx = blockIdx.x*64, cx = blockIdx.y*64, b = blockIdx.z;
    const int tid = threadIdx.x;
    {   // read [64 t][64 c] coalesced
        int r = tid >> 2, c0 = (tid & 3) * 16;
        size_t base = ((size_t)(b*NT + tx + r))*NC + cx + c0;
        #pragma unroll
        for (int j=0;j<16;j+=4){
            float4 k4 = *(const float4*)&kf[base+j];
            float4 v4 = *(const float4*)&vf[base+j];
            tile[r][c0+j+0] = f2bf(k4.x*v4.x);
            tile[r][c0+j+1] = f2bf(k4.y*v4.y);
            tile[r][c0+j+2] = f2bf(k4.z*v4.z);
            tile[r][c0+j+3] = f2bf(k4.w*v4.w);
        }
    }
    __syncthreads();
    #pragma unroll
    for (int rep=0;rep<2;rep++){    // write [64 c][64 t] coalesced (short8)
        int row = (tid >> 3) + rep*32;   // c-local
        int cs = (tid & 7) * 8;          // t-local
        short8 vv;
        #pragma unroll
        for (int j=0;j<8;j++) vv[j] = (short)tile[cs+j][row];
        *(short8*)&kvt[((size_t)(b*NC + cx + row))*NT + tx + cs] = vv;
    }
}

// ---- cumsum of k over T: chunk partials, then offset + local scan ----
__global__ void scan1(const float* __restrict__ kf, float* __restrict__ part){
    int gid = blockIdx.x*256 + threadIdx.x;  // B*NCH*C = 65536
    int c = gid & 255, ch = (gid >> 8) & 15, b = gid >> 12;
    const float* p = kf + ((size_t)b*NT + ch*NCL)*NC + c;
    float s = 0.f;
    for (int i=0;i<NCL;i++) s += p[(size_t)i*NC];
    part[gid] = s;
}
__global__ void scan2(const float* __restrict__ kf, const float* __restrict__ part,
                      float* __restrict__ sumk){
    int gid = blockIdx.x*256 + threadIdx.x;
    int c = gid & 255, ch = (gid >> 8) & 15, b = gid >> 12;
    float off = 0.f;
    for (int j=0;j<ch;j++) off += part[((b*NCH + j)<<8) + c];
    const float* p = kf + ((size_t)b*NT + ch*NCL)*NC + c;
    float* o = sumk + ((size_t)b*NT + ch*NCL)*NC + c;
    float s = off;
    for (int i=0;i<NCL;i++){ s += p[(size_t)i*NC]; o[(size_t)i*NC] = s; }
}

// ---- wkv[b] = W_toeplitz @ kv[b]; A rows are windows of twb table ----
__global__ __launch_bounds__(256) void gemm_wkv(const unsigned short* __restrict__ twb,
                                                const unsigned short* __restrict__ kvt,
                                                float* __restrict__ wkv){
    __shared__ unsigned short As[64][40];
    __shared__ unsigned short Bs[64][40];
    const int tid = threadIdx.x;
    const int lane = tid & 63, w = tid >> 6;
    const int wm = (w >> 1) * 32, wn = (w & 1) * 32;
    const int r = tid >> 2, kk = (tid & 3) << 3;
    const int t_base = blockIdx.x * 64, c_base = blockIdx.y * 64, b = blockIdx.z;
    const int lrow = lane & 15, krow = (lane >> 4) << 3;
    const unsigned short* kvb = kvt + (size_t)b*NC*NT;
    f32x4 acc[2][2] = {};
    const int kend = t_base + 64;            // skip all-zero upper-triangle K blocks
    const int abase = 2047 - (t_base + r);   // W[t][u] = twb[2047 - t + u]
    for (int u0 = 0; u0 < kend; u0 += 32) {
        short8 av;
        #pragma unroll
        for (int j=0;j<8;j++) av[j] = (short)twb[abase + u0 + kk + j];
        *(short8*)&As[r][kk] = av;
        *(short8*)&Bs[r][kk] = *(const short8*)&kvb[(size_t)(c_base + r)*NT + u0 + kk];
        __syncthreads();
        short8 a0 = *(const short8*)&As[wm + lrow][krow];
        short8 a1 = *(const short8*)&As[wm + 16 + lrow][krow];
        short8 b0 = *(const short8*)&Bs[wn + lrow][krow];
        short8 b1 = *(const short8*)&Bs[wn + 16 + lrow][krow];
        acc[0][0] = __builtin_amdgcn_mfma_f32_16x16x32_bf16(a0,b0,acc[0][0],0,0,0);
        acc[0][1] = __builtin_amdgcn_mfma_f32_16x16x32_bf16(a0,b1,acc[0][1],0,0,0);
        acc[1][0] = __builtin_amdgcn_mfma_f32_16x16x32_bf16(a1,b0,acc[1][0],0,0,0);
        acc[1][1] = __builtin_amdgcn_mfma_f32_16x16x32_bf16(a1,b1,acc[1][1],0,0,0);
        __syncthreads();
    }
    const int orow = t_base + wm + ((lane >> 4) << 2);
    const int ocol = c_base + wn + lrow;
    float* outb = wkv + (size_t)b*NT*NC;
    #pragma unroll
    for (int mi=0;mi<2;mi++)
    #pragma unroll
    for (int ni=0;ni<2;ni++)
    #pragma unroll
    for (int i=0;i<4;i++)
        outb[(size_t)(orow + mi*16 + i)*NC + ocol + ni*16] = acc[mi][ni][i];
}

// ---- rwkv = sigmoid(r) * wkv / sumk -> bf16 ----
__global__ void rwkv_kernel(const float* __restrict__ sr, const float* __restrict__ wkv,
                            const float* __restrict__ sumk, unsigned short* __restrict__ rb){
    int gid = blockIdx.x*256 + threadIdx.x;   // NM*NC/8
    size_t base = (size_t)gid*8;
    short8 o;
    #pragma unroll
    for (int j=0;j<8;j+=4){
        float4 s4 = *(const float4*)&sr[base+j];
        float4 w4 = *(const float4*)&wkv[base+j];
        float4 k4 = *(const float4*)&sumk[base+j];
        o[j+0]=(short)f2bf(s4.x*w4.x/k4.x);
        o[j+1]=(short)f2bf(s4.y*w4.y/k4.y);
        o[j+2]=(short)f2bf(s4.z*w4.z/k4.z);
        o[j+3]=(short)f2bf(s4.w*w4.w/k4.w);
    }
    *(short8*)&rb[base] = o;
}

extern "C" void kernel_launch(void* const* d_in, const int* in_sizes, int n_in,
                              void* d_out, int out_size, void* d_ws, size_t ws_size,
                              hipStream_t stream) {
    const float* x   = (const float*)d_in[0];
    const float* tw  = (const float*)d_in[1];
    const float* tmk = (const float*)d_in[2];
    const float* tmv = (const float*)d_in[3];
    const float* tmr = (const float*)d_in[4];
    const float* Wk  = (const float*)d_in[5];
    const float* Wv  = (const float*)d_in[6];
    const float* Wr  = (const float*)d_in[7];
    const float* Wo  = (const float*)d_in[8];

    char* ws = (char*)d_ws;
    const size_t MC = (size_t)NM*NC;   // 8,388,608
    unsigned short* xk  = (unsigned short*)(ws);            // bf16 MC
    unsigned short* xv  = (unsigned short*)(ws + MC*2);     // bf16 MC
    unsigned short* xr  = (unsigned short*)(ws + MC*4);     // bf16 MC
    float* kf   = (float*)(ws + MC*6);                      // f32 MC
    float* vf   = (float*)(ws + MC*10);                     // f32 MC
    float* srf  = (float*)(ws + MC*14);                     // f32 MC (sigmoid(r))
    float* sumk = (float*)(ws + MC*18);                     // f32 MC
    unsigned short* twb = (unsigned short*)(ws + MC*22);    // 4096 bf16 (zero-padded)
    unsigned short* WkT = (unsigned short*)(ws + MC*22 + 8192);
    unsigned short* WvT = WkT + NC*NC;
    unsigned short* WrT = WvT + NC*NC;
    unsigned short* WoT = WrT + NC*NC;
    float* part = (float*)(ws + MC*22 + 8192 + 4*(size_t)NC*NC*2);  // 65536 f32
    // buffer reuse (stream-serialized, producers strictly after consumers):
    unsigned short* kvt   = xv;   // xv dead after v-GEMM
    float*          wkvf  = kf;   // kf dead after scan2
    unsigned short* rwkvb = xk;   // xk dead after k-GEMM

    prep_kernel<<<256,256,0,stream>>>(tw, Wk,Wv,Wr,Wo, twb, WkT,WvT,WrT,WoT);
    mix_kernel<<<(int)(MC/8/256),256,0,stream>>>(x,tmk,tmv,tmr,xk,xv,xr);
    gemm_c<1><<<dim3(NM/64,NC/64),256,0,stream>>>(xk,WkT,kf);
    gemm_c<0><<<dim3(NM/64,NC/64),256,0,stream>>>(xv,WvT,vf);
    gemm_c<2><<<dim3(NM/64,NC/64),256,0,stream>>>(xr,WrT,srf);
    kv_kernel<<<dim3(NT/64,NC/64,NB),256,0,stream>>>(kf,vf,kvt);
    scan1<<<256,256,0,stream>>>(kf,part);
    scan2<<<256,256,0,stream>>>(kf,part,sumk);
    gemm_wkv<<<dim3(NT/64,NC/64,NB),256,0,stream>>>(twb,kvt,wkvf);
    rwkv_kernel<<<(int)(MC/8/256),256,0,stream>>>(srf,wkvf,sumk,rwkvb);
    gemm_c<0><<<dim3(NM/64,NC/64),256,0,stream>>>(rwkvb,WoT,(float*)d_out);
}

// Round 2
// 141.243 us; speedup vs baseline: 1.4631x; 1.4631x over previous
//
#include <hip/hip_runtime.h>
#include <hip/hip_bf16.h>

#define NB 16
#define NT 2048
#define NC 256
#define NM (NB*NT)          // 32768 rows
#define NCH 16              // cumsum chunks
#define NCL (NT/NCH)        // 128 per chunk

typedef __attribute__((ext_vector_type(8))) short short8;
typedef __attribute__((ext_vector_type(4))) float f32x4;

__device__ __forceinline__ unsigned short f2bf(float x){
    union { float f; unsigned u; } v; v.f = x;
    unsigned r = v.u + 0x7FFFu + ((v.u >> 16) & 1u);   // RNE
    return (unsigned short)(r >> 16);
}
__device__ __forceinline__ float bf2f(unsigned short x){
    union { unsigned u; float f; } v; v.u = ((unsigned)x) << 16;
    return v.f;
}
__device__ __forceinline__ void gload16(const unsigned short* g, unsigned short* l){
    __builtin_amdgcn_global_load_lds((const __attribute__((address_space(1))) void*)g,
                                     (__attribute__((address_space(3))) void*)l, 16, 0, 0);
}

// Swizzle convention (st-16x32 style, chunk = 16B = 8 bf16):
// physical col' = (col & ~63) | ((((col>>3)&7) ^ (row&7)) << 3) | (col & 7)
// Producers write physical; GEMMs global_load_lds linearly; ds_read XORs back.

// ---- prep: swizzled transposed bf16 weights + expanded Toeplitz A panels ----
// Aexp[Didx][r][chunk_lin][j] (32 x 128 x 64 bf16), Didx -> D = Didx*64 - 1920:
//   logical A[r][k] = tw[2047 + D - r + k] (0 outside [0,2048))
__global__ void prep_kernel(const float* __restrict__ tw,
                            const float* __restrict__ Wk, const float* __restrict__ Wv,
                            const float* __restrict__ Wr, const float* __restrict__ Wo,
                            unsigned short* __restrict__ WkT, unsigned short* __restrict__ WvT,
                            unsigned short* __restrict__ WrT, unsigned short* __restrict__ WoT,
                            unsigned short* __restrict__ Aexp){
    int gid = blockIdx.x*256 + threadIdx.x;          // 65536 threads
    {
        int n = gid >> 8, u = gid & 255;
        int usw = (u & ~63) | ((((u>>3)&7) ^ (n&7)) << 3) | (u & 7);
        int src = u*NC + n;                           // WT[n][u] = W[u][n]
        WkT[n*NC + usw] = f2bf(Wk[src]);
        WvT[n*NC + usw] = f2bf(Wv[src]);
        WrT[n*NC + usw] = f2bf(Wr[src]);
        WoT[n*NC + usw] = f2bf(Wo[src]);
    }
    if (gid < 32768){
        int Di = gid >> 10, rem = gid & 1023;
        int r = rem >> 3, ql = rem & 7;
        int qlog = ql ^ (r & 7);
        int D = Di*64 - 1920;
        short8 vv;
        #pragma unroll
        for (int j = 0; j < 8; j++){
            int idx = 2047 + D - r + qlog*8 + j;
            float val = (idx >= 0 && idx < NT) ? tw[idx] : 0.f;
            vv[j] = (short)f2bf(val);
        }
        *(short8*)&Aexp[(size_t)gid*8] = vv;
    }
}

// ---- time-shift mix -> xk/xv/xr (bf16, swizzled GEMM-A layout) ----
__global__ void mix_kernel(const float* __restrict__ x,
                           const float* __restrict__ tmk, const float* __restrict__ tmv,
                           const float* __restrict__ tmr,
                           unsigned short* __restrict__ xk, unsigned short* __restrict__ xv,
                           unsigned short* __restrict__ xr){
    int gid = blockIdx.x*256 + threadIdx.x;           // NM*NC/8
    int m = gid >> 5;
    int c0 = (gid & 31) << 3;
    int t = m & (NT-1);
    size_t base = (size_t)m*NC + c0;
    float xa[8], xb[8];
    #pragma unroll
    for (int j=0;j<8;j+=4) *(float4*)&xa[j] = *(const float4*)&x[base+j];
    if (t > 0) {
        #pragma unroll
        for (int j=0;j<8;j+=4) *(float4*)&xb[j] = *(const float4*)&x[base - NC + j];
    } else {
        #pragma unroll
        for (int j=0;j<8;j++) xb[j]=0.f;
    }
    short8 ok, ov, orr;
    #pragma unroll
    for (int j=0;j<8;j++){
        float mk = tmk[c0+j], mv = tmv[c0+j], mr = tmr[c0+j];
        ok[j]  = (short)f2bf(xa[j]*mk + xb[j]*(1.f-mk));
        ov[j]  = (short)f2bf(xa[j]*mv + xb[j]*(1.f-mv));
        orr[j] = (short)f2bf(xa[j]*mr + xb[j]*(1.f-mr));
    }
    int csw = (c0 & ~63) | ((((c0>>3)&7) ^ (m&7)) << 3);
    size_t dst = (size_t)m*NC + csw;
    *(short8*)&xk[dst] = ok;
    *(short8*)&xv[dst] = ov;
    *(short8*)&xr[dst] = orr;
}

// ---- 128x128-tile bf16 MFMA GEMM, [M,256]@[256,256], K staged via gload_lds ----
// MODE 0: f32 plain, 1: f32 exp(clip), 2: bf16 plain, 3: bf16 sigmoid
template<int MODE>
__global__ __launch_bounds__(256) void gemm_c(const unsigned short* __restrict__ A,
                                              const unsigned short* __restrict__ BT,
                                              void* __restrict__ outp){
    __shared__ unsigned short As[2][128*64];
    __shared__ unsigned short Bs[2][128*64];
    const int tid = threadIdx.x;
    const int lane = tid & 63, w = tid >> 6;
    const int wm = (w >> 1) * 64, wn = (w & 1) * 64;
    const int m0 = blockIdx.x * 128, n0 = blockIdx.y * 128;
    const int lrow = lane & 15, kgrp = lane >> 4, lx = lane & 7;
    const int qrow = tid >> 3, qc = tid & 7;

    f32x4 acc[4][4] = {};

    auto STAGE = [&](int buf, int k0){
        #pragma unroll
        for (int i=0;i<4;i++){
            int row = qrow + 32*i;
            int q = row*8 + qc;
            gload16(A  + (size_t)(m0+row)*NC + k0 + qc*8, &As[buf][q*8]);
            gload16(BT + (size_t)(n0+row)*NC + k0 + qc*8, &Bs[buf][q*8]);
        }
    };

    STAGE(0, 0);
    __syncthreads();
    for (int s = 0; s < 4; ++s){
        if (s < 3) STAGE((s+1)&1, (s+1)*64);
        const unsigned short* as = As[s&1];
        const unsigned short* bs = Bs[s&1];
        #pragma unroll
        for (int ks = 0; ks < 2; ++ks){
            const int lk = ks*4 + kgrp;
            const int ch = (lk ^ lx) << 3;
            short8 a[4], b[4];
            #pragma unroll
            for (int mi=0;mi<4;mi++) a[mi] = *(const short8*)&as[(wm + mi*16 + lrow)*64 + ch];
            #pragma unroll
            for (int ni=0;ni<4;ni++) b[ni] = *(const short8*)&bs[(wn + ni*16 + lrow)*64 + ch];
            #pragma unroll
            for (int mi=0;mi<4;mi++)
            #pragma unroll
            for (int ni=0;ni<4;ni++)
                acc[mi][ni] = __builtin_amdgcn_mfma_f32_16x16x32_bf16(a[mi], b[ni], acc[mi][ni], 0,0,0);
        }
        __syncthreads();
    }

    const int orow = m0 + wm + kgrp*4;
    const int ocol = n0 + wn + lrow;
    #pragma unroll
    for (int mi=0;mi<4;mi++)
    #pragma unroll
    for (int ni=0;ni<4;ni++)
    #pragma unroll
    for (int i=0;i<4;i++){
        float vv = acc[mi][ni][i];
        size_t off = (size_t)(orow + mi*16 + i)*NC + ocol + ni*16;
        if (MODE == 0) ((float*)outp)[off] = vv;
        if (MODE == 1) ((float*)outp)[off] = __expf(fminf(fmaxf(vv,-60.f),30.f));
        if (MODE == 2) ((unsigned short*)outp)[off] = f2bf(vv);
        if (MODE == 3) ((unsigned short*)outp)[off] = f2bf(1.f/(1.f+__expf(-vv)));
    }
}

// ---- kv = k*v, stored transposed [B][C][T] bf16, pre-swizzled for GEMM-B ----
__global__ __launch_bounds__(256) void kv_kernel(const float* __restrict__ kf,
                                                 const unsigned short* __restrict__ vb,
                                                 unsigned short* __restrict__ kvt){
    __shared__ unsigned short tile[64][65];
    const int tx = blockIdx.x*64, cx = blockIdx.y*64, b = blockIdx.z;
    const int tid = threadIdx.x;
    {
        int r = tid >> 2, c0 = (tid & 3) * 16;
        size_t base = ((size_t)(b*NT + tx + r))*NC + cx + c0;
        short8 v8a = *(const short8*)&vb[base];
        short8 v8b = *(const short8*)&vb[base+8];
        #pragma unroll
        for (int j=0;j<16;j+=4){
            float4 k4 = *(const float4*)&kf[base+j];
            float f0 = (j<8)? bf2f((unsigned short)v8a[j&7])   : bf2f((unsigned short)v8b[j&7]);
            float f1 = (j<8)? bf2f((unsigned short)v8a[(j&7)+1]) : bf2f((unsigned short)v8b[(j&7)+1]);
            float f2 = (j<8)? bf2f((unsigned short)v8a[(j&7)+2]) : bf2f((unsigned short)v8b[(j&7)+2]);
            float f3 = (j<8)? bf2f((unsigned short)v8a[(j&7)+3]) : bf2f((unsigned short)v8b[(j&7)+3]);
            tile[r][c0+j+0] = f2bf(k4.x*f0);
            tile[r][c0+j+1] = f2bf(k4.y*f1);
            tile[r][c0+j+2] = f2bf(k4.z*f2);
            tile[r][c0+j+3] = f2bf(k4.w*f3);
        }
    }
    __syncthreads();
    #pragma unroll
    for (int rep=0;rep<2;rep++){
        int row = (tid >> 3) + rep*32;   // c-local
        int cs = (tid & 7) * 8;          // t-local logical chunk*8
        short8 vv;
        #pragma unroll
        for (int j=0;j<8;j++) vv[j] = (short)tile[cs+j][row];
        int csw = ((cs>>3) ^ (row&7)) << 3;           // physical chunk
        *(short8*)&kvt[((size_t)(b*NC + cx + row))*NT + tx + csw] = vv;
    }
}

// ---- cumsum of k over T ----
__global__ void scan1(const float* __restrict__ kf, float* __restrict__ part){
    int gid = blockIdx.x*256 + threadIdx.x;  // B*NCH*C = 65536
    int c = gid & 255, ch = (gid >> 8) & 15, b = gid >> 12;
    const float* p = kf + ((size_t)b*NT + ch*NCL)*NC + c;
    float s = 0.f;
    for (int i=0;i<NCL;i++) s += p[(size_t)i*NC];
    part[gid] = s;
}
__global__ void scan2(const float* __restrict__ kf, const float* __restrict__ part,
                      float* __restrict__ sumk){
    int gid = blockIdx.x*256 + threadIdx.x;
    int c = gid & 255, ch = (gid >> 8) & 15, b = gid >> 12;
    float off = 0.f;
    for (int j=0;j<ch;j++) off += part[((b*NCH + j)<<8) + c];
    const float* p = kf + ((size_t)b*NT + ch*NCL)*NC + c;
    float* o = sumk + ((size_t)b*NT + ch*NCL)*NC + c;
    float s = off;
    for (int i=0;i<NCL;i++){ s += p[(size_t)i*NC]; o[(size_t)i*NC] = s; }
}

// ---- wkv = Toeplitz @ kv, fused epilogue: sigmoid(r)*wkv/sumk -> bf16 swz ----
__global__ __launch_bounds__(256) void gemm_wkv(const unsigned short* __restrict__ Aexp,
                                                const unsigned short* __restrict__ kvt,
                                                const unsigned short* __restrict__ srb,
                                                const float* __restrict__ sumk,
                                                unsigned short* __restrict__ rout){
    __shared__ unsigned short As[2][128*64];
    __shared__ unsigned short Bs[2][128*64];
    const int tid = threadIdx.x;
    const int lane = tid & 63, w = tid >> 6;
    const int wm = (w >> 1) * 64, wn = (w & 1) * 64;
    const int lrow = lane & 15, kgrp = lane >> 4, lx = lane & 7;
    const int qrow = tid >> 3, qc = tid & 7;

    // heavy/light pairing: blocks i and i+256 sum to constant work
    const int id = blockIdx.x;
    const int j = id & 255, hi = id >> 8;
    const int t_idx = hi ? (15 - (j >> 4)) : (j >> 4);
    const int cb = (j & 15) | (hi << 4);
    const int c0 = (cb & 1) * 128;
    const int b  = cb >> 1;
    const int t0 = t_idx * 128;
    const int nsteps = t_idx*2 + 2;
    const unsigned short* Ab = Aexp + (size_t)(30 - 2*t_idx)*8192;  // 16KB tiles, consecutive per step

    f32x4 acc[4][4] = {};

    auto STAGE = [&](int buf, int s){
        const int u0 = s*64;
        #pragma unroll
        for (int i=0;i<4;i++){
            int row = qrow + 32*i;
            int q = row*8 + qc;
            gload16(Ab + (size_t)s*8192 + (size_t)q*8, &As[buf][q*8]);
            gload16(kvt + ((size_t)b*NC + c0 + row)*NT + u0 + qc*8, &Bs[buf][q*8]);
        }
    };

    STAGE(0, 0);
    __syncthreads();
    for (int s = 0; s < nsteps; ++s){
        if (s+1 < nsteps) STAGE((s+1)&1, s+1);
        const unsigned short* as = As[s&1];
        const unsigned short* bs = Bs[s&1];
        #pragma unroll
        for (int ks = 0; ks < 2; ++ks){
            const int lk = ks*4 + kgrp;
            const int ch = (lk ^ lx) << 3;
            short8 a[4], b8[4];
            #pragma unroll
            for (int mi=0;mi<4;mi++) a[mi]  = *(const short8*)&as[(wm + mi*16 + lrow)*64 + ch];
            #pragma unroll
            for (int ni=0;ni<4;ni++) b8[ni] = *(const short8*)&bs[(wn + ni*16 + lrow)*64 + ch];
            #pragma unroll
            for (int mi=0;mi<4;mi++)
            #pragma unroll
            for (int ni=0;ni<4;ni++)
                acc[mi][ni] = __builtin_amdgcn_mfma_f32_16x16x32_bf16(a[mi], b8[ni], acc[mi][ni], 0,0,0);
        }
        __syncthreads();
    }

    // fused epilogue: rout[t][col_swz] = bf16(sigmoid_r * wkv / sumk)
    const int orow = wm + kgrp*4;
    const int ocol = c0 + wn + lrow;
    #pragma unroll
    for (int mi=0;mi<4;mi++)
    #pragma unroll
    for (int ni=0;ni<4;ni++)
    #pragma unroll
    for (int i=0;i<4;i++){
        int t = t0 + orow + mi*16 + i;
        int col = ocol + ni*16;
        size_t g = (size_t)(b*NT + t)*NC + col;
        float sr = bf2f(srb[g]);
        float sk = sumk[g];
        float vv = sr * acc[mi][ni][i] / sk;
        int csw = (col & ~63) | ((((col>>3)&7) ^ (t&7)) << 3) | (col & 7);
        rout[(size_t)(b*NT + t)*NC + csw] = f2bf(vv);
    }
}

extern "C" void kernel_launch(void* const* d_in, const int* in_sizes, int n_in,
                              void* d_out, int out_size, void* d_ws, size_t ws_size,
                              hipStream_t stream) {
    const float* x   = (const float*)d_in[0];
    const float* tw  = (const float*)d_in[1];
    const float* tmk = (const float*)d_in[2];
    const float* tmv = (const float*)d_in[3];
    const float* tmr = (const float*)d_in[4];
    const float* Wk  = (const float*)d_in[5];
    const float* Wv  = (const float*)d_in[6];
    const float* Wr  = (const float*)d_in[7];
    const float* Wo  = (const float*)d_in[8];

    char* ws = (char*)d_ws;
    const size_t MC = (size_t)NM*NC;   // 8,388,608
    unsigned short* xk   = (unsigned short*)(ws);             // bf16 MC (swz)
    unsigned short* xv   = (unsigned short*)(ws + MC*2);      // bf16 MC (swz)
    unsigned short* xr   = (unsigned short*)(ws + MC*4);      // bf16 MC (swz)
    float*          kf   = (float*)(ws + MC*6);               // f32 MC
    unsigned short* vb   = (unsigned short*)(ws + MC*10);     // bf16 MC
    unsigned short* srb  = (unsigned short*)(ws + MC*12);     // bf16 MC (sigmoid r)
    float*          sumk = (float*)(ws + MC*14);              // f32 MC
    unsigned short* kvt  = (unsigned short*)(ws + MC*18);     // bf16 MC (swz, [B][C][T])
    unsigned short* Aexp = (unsigned short*)(ws + MC*20);     // 512KB
    unsigned short* WkT  = (unsigned short*)(ws + MC*20 + 524288);
    unsigned short* WvT  = WkT + NC*NC;
    unsigned short* WrT  = WvT + NC*NC;
    unsigned short* WoT  = WrT + NC*NC;
    float*          part = (float*)(ws + MC*20 + 1048576);    // 256KB
    unsigned short* rwkvb = xk;   // xk dead after k-GEMM

    prep_kernel<<<256,256,0,stream>>>(tw, Wk,Wv,Wr,Wo, WkT,WvT,WrT,WoT, Aexp);
    mix_kernel<<<(int)(MC/8/256),256,0,stream>>>(x,tmk,tmv,tmr,xk,xv,xr);
    gemm_c<1><<<dim3(NM/128,NC/128),256,0,stream>>>(xk,WkT,kf);
    gemm_c<2><<<dim3(NM/128,NC/128),256,0,stream>>>(xv,WvT,vb);
    gemm_c<3><<<dim3(NM/128,NC/128),256,0,stream>>>(xr,WrT,srb);
    kv_kernel<<<dim3(NT/64,NC/64,NB),256,0,stream>>>(kf,vb,kvt);
    scan1<<<256,256,0,stream>>>(kf,part);
    scan2<<<256,256,0,stream>>>(kf,part,sumk);
    gemm_wkv<<<512,256,0,stream>>>(Aexp,kvt,srb,sumk,rwkvb);
    gemm_c<0><<<dim3(NM/128,NC/128),256,0,stream>>>(rwkvb,WoT,(float*)d_out);
}

// Round 4
// 138.890 us; speedup vs baseline: 1.4879x; 1.0169x over previous
//
#include <hip/hip_runtime.h>
#include <hip/hip_bf16.h>

#define NB 16
#define NT 2048
#define NC 256
#define NM (NB*NT)          // 32768 rows
#define NCH 16              // cumsum chunks
#define NCL (NT/NCH)        // 128 per chunk

typedef __attribute__((ext_vector_type(8))) short short8;
typedef __attribute__((ext_vector_type(4))) short short4v;
typedef __attribute__((ext_vector_type(4))) unsigned short ushort4v;
typedef __attribute__((ext_vector_type(4))) float f32x4;

__device__ __forceinline__ unsigned short f2bf(float x){
    union { float f; unsigned u; } v; v.f = x;
    unsigned r = v.u + 0x7FFFu + ((v.u >> 16) & 1u);   // RNE
    return (unsigned short)(r >> 16);
}
__device__ __forceinline__ float bf2f(unsigned short x){
    union { unsigned u; float f; } v; v.u = ((unsigned)x) << 16;
    return v.f;
}
__device__ __forceinline__ void gload16(const unsigned short* g, unsigned short* l){
    __builtin_amdgcn_global_load_lds((const __attribute__((address_space(1))) void*)g,
                                     (__attribute__((address_space(3))) void*)l, 16, 0, 0);
}

// Swizzle convention (chunk = 16B = 8 bf16):
// physical col' = (col & ~63) | ((((col>>3)&7) ^ (row&7)) << 3) | (col & 7)
// Producers write physical; GEMMs global_load_lds linearly; ds_read XORs back.

// ---- prep: swizzled transposed bf16 weights + expanded Toeplitz A panels ----
__global__ void prep_kernel(const float* __restrict__ tw,
                            const float* __restrict__ Wk, const float* __restrict__ Wv,
                            const float* __restrict__ Wr, const float* __restrict__ Wo,
                            unsigned short* __restrict__ WkT, unsigned short* __restrict__ WvT,
                            unsigned short* __restrict__ WrT, unsigned short* __restrict__ WoT,
                            unsigned short* __restrict__ Aexp){
    int gid = blockIdx.x*256 + threadIdx.x;          // 65536 threads
    {
        int n = gid >> 8, u = gid & 255;
        int usw = (u & ~63) | ((((u>>3)&7) ^ (n&7)) << 3) | (u & 7);
        int src = u*NC + n;                           // WT[n][u] = W[u][n]
        WkT[n*NC + usw] = f2bf(Wk[src]);
        WvT[n*NC + usw] = f2bf(Wv[src]);
        WrT[n*NC + usw] = f2bf(Wr[src]);
        WoT[n*NC + usw] = f2bf(Wo[src]);
    }
    if (gid < 32768){
        int Di = gid >> 10, rem = gid & 1023;
        int r = rem >> 3, ql = rem & 7;
        int qlog = ql ^ (r & 7);
        int D = Di*64 - 1920;
        short8 vv;
        #pragma unroll
        for (int j = 0; j < 8; j++){
            int idx = 2047 + D - r + qlog*8 + j;
            float val = (idx >= 0 && idx < NT) ? tw[idx] : 0.f;
            vv[j] = (short)f2bf(val);
        }
        *(short8*)&Aexp[(size_t)gid*8] = vv;
    }
}

// ---- time-shift mix -> xk/xv/xr (bf16, swizzled GEMM-A layout) ----
__global__ void mix_kernel(const float* __restrict__ x,
                           const float* __restrict__ tmk, const float* __restrict__ tmv,
                           const float* __restrict__ tmr,
                           unsigned short* __restrict__ xk, unsigned short* __restrict__ xv,
                           unsigned short* __restrict__ xr){
    int gid = blockIdx.x*256 + threadIdx.x;           // NM*NC/8
    int m = gid >> 5;
    int c0 = (gid & 31) << 3;
    int t = m & (NT-1);
    size_t base = (size_t)m*NC + c0;
    float xa[8], xb[8];
    #pragma unroll
    for (int j=0;j<8;j+=4) *(float4*)&xa[j] = *(const float4*)&x[base+j];
    if (t > 0) {
        #pragma unroll
        for (int j=0;j<8;j+=4) *(float4*)&xb[j] = *(const float4*)&x[base - NC + j];
    } else {
        #pragma unroll
        for (int j=0;j<8;j++) xb[j]=0.f;
    }
    short8 ok, ov, orr;
    #pragma unroll
    for (int j=0;j<8;j++){
        float mk = tmk[c0+j], mv = tmv[c0+j], mr = tmr[c0+j];
        ok[j]  = (short)f2bf(xa[j]*mk + xb[j]*(1.f-mk));
        ov[j]  = (short)f2bf(xa[j]*mv + xb[j]*(1.f-mv));
        orr[j] = (short)f2bf(xa[j]*mr + xb[j]*(1.f-mr));
    }
    int csw = (c0 & ~63) | ((((c0>>3)&7) ^ (m&7)) << 3);
    size_t dst = (size_t)m*NC + csw;
    *(short8*)&xk[dst] = ok;
    *(short8*)&xv[dst] = ov;
    *(short8*)&xr[dst] = orr;
}

// ---- 128x128-tile bf16 MFMA GEMM, [M,256]@[256,256] ----
// MODE 0: f32 plain out
// MODE 3: bf16 sigmoid plain out
// MODE 4: bf16 out TRANSPOSED [B][C][T] (for v)
// MODE 5: k-GEMM: f32 exp(clip) out + fused kv=k*v written to kvt [B][C][T] swizzled
template<int MODE>
__global__ __launch_bounds__(256) void gemm_c(const unsigned short* __restrict__ A,
                                              const unsigned short* __restrict__ BT,
                                              void* __restrict__ outp,
                                              const unsigned short* __restrict__ vbT,
                                              unsigned short* __restrict__ kvt){
    __shared__ unsigned short smem[32768];   // 64KB: As[2][8192] | Bs[2][8192]
    unsigned short* As0 = smem;
    unsigned short* Bs0 = smem + 16384;
    const int tid = threadIdx.x;
    const int lane = tid & 63, w = tid >> 6;
    const int wm = (w >> 1) * 64, wn = (w & 1) * 64;
    const int m0 = blockIdx.x * 128, n0 = blockIdx.y * 128;
    const int lrow = lane & 15, kgrp = lane >> 4, lx = lane & 7;
    const int qrow = tid >> 3, qc = tid & 7;

    f32x4 acc[4][4] = {};

    auto STAGE = [&](int buf, int k0){
        #pragma unroll
        for (int i=0;i<4;i++){
            int row = qrow + 32*i;
            int q = row*8 + qc;
            gload16(A  + (size_t)(m0+row)*NC + k0 + qc*8, As0 + buf*8192 + q*8);
            gload16(BT + (size_t)(n0+row)*NC + k0 + qc*8, Bs0 + buf*8192 + q*8);
        }
    };

    STAGE(0, 0);
    __syncthreads();
    for (int s = 0; s < 4; ++s){
        if (s < 3) STAGE((s+1)&1, (s+1)*64);
        const unsigned short* as = As0 + (s&1)*8192;
        const unsigned short* bs = Bs0 + (s&1)*8192;
        #pragma unroll
        for (int ks = 0; ks < 2; ++ks){
            const int lk = ks*4 + kgrp;
            const int ch = (lk ^ lx) << 3;
            short8 a[4], b[4];
            #pragma unroll
            for (int mi=0;mi<4;mi++) a[mi] = *(const short8*)&as[(wm + mi*16 + lrow)*64 + ch];
            #pragma unroll
            for (int ni=0;ni<4;ni++) b[ni] = *(const short8*)&bs[(wn + ni*16 + lrow)*64 + ch];
            #pragma unroll
            for (int mi=0;mi<4;mi++)
            #pragma unroll
            for (int ni=0;ni<4;ni++)
                acc[mi][ni] = __builtin_amdgcn_mfma_f32_16x16x32_bf16(a[mi], b[ni], acc[mi][ni], 0,0,0);
        }
        __syncthreads();
    }

    const int orow = wm + kgrp*4;      // local row base
    const int ocol = wn + lrow;        // local col base
    if (MODE == 0 || MODE == 3){
        #pragma unroll
        for (int mi=0;mi<4;mi++)
        #pragma unroll
        for (int ni=0;ni<4;ni++)
        #pragma unroll
        for (int i=0;i<4;i++){
            float vv = acc[mi][ni][i];
            size_t off = (size_t)(m0 + orow + mi*16 + i)*NC + n0 + ocol + ni*16;
            if (MODE == 0) ((float*)outp)[off] = vv;
            if (MODE == 3) ((unsigned short*)outp)[off] = f2bf(1.f/(1.f+__expf(-vv)));
        }
    } else {
        const int b = m0 >> 11, t0b = m0 & 2047;
        unsigned short (*tileT)[136] = (unsigned short (*)[136])smem;  // [c 128][t 128+8]
        #pragma unroll
        for (int mi=0;mi<4;mi++)
        #pragma unroll
        for (int ni=0;ni<4;ni++){
            const int cL = ocol + ni*16;      // local c
            const int t4 = orow + mi*16;      // local t (4 consecutive)
            short4v pk;
            if (MODE == 5){
                ushort4v v4 = *(const ushort4v*)&vbT[((size_t)(b*NC + n0 + cL))*NT + t0b + t4];
                #pragma unroll
                for (int i=0;i<4;i++){
                    float ke = __expf(fminf(fmaxf(acc[mi][ni][i],-60.f),30.f));
                    ((float*)outp)[(size_t)(m0 + t4 + i)*NC + n0 + cL] = ke;
                    pk[i] = (short)f2bf(ke * bf2f(v4[i]));
                }
            } else {
                #pragma unroll
                for (int i=0;i<4;i++) pk[i] = (short)f2bf(acc[mi][ni][i]);
            }
            *(short4v*)&tileT[cL][t4] = pk;
        }
        __syncthreads();
        #pragma unroll
        for (int p=0;p<8;p++){
            int c = (tid >> 4) + p*16;
            int t8 = (tid & 15) * 8;
            short8 vv = *(const short8*)&tileT[c][t8];
            if (MODE == 4){
                *(short8*)&((unsigned short*)outp)[((size_t)(b*NC + n0 + c))*NT + t0b + t8] = vv;
            } else {
                int row = n0 + c;
                int colp = (t8 & ~63) | ((((t8>>3)&7) ^ (row&7)) << 3);
                *(short8*)&kvt[((size_t)(b*NC + row))*NT + t0b + colp] = vv;
            }
        }
    }
}

// ---- cumsum of k over T ----
__global__ void scan1(const float* __restrict__ kf, float* __restrict__ part){
    int gid = blockIdx.x*256 + threadIdx.x;  // B*NCH*C = 65536
    int c = gid & 255, ch = (gid >> 8) & 15, b = gid >> 12;
    const float* p = kf + ((size_t)b*NT + ch*NCL)*NC + c;
    float s = 0.f;
    for (int i=0;i<NCL;i++) s += p[(size_t)i*NC];
    part[gid] = s;
}
__global__ void scan2(const float* __restrict__ kf, const float* __restrict__ part,
                      float* __restrict__ sumk){
    int gid = blockIdx.x*256 + threadIdx.x;
    int c = gid & 255, ch = (gid >> 8) & 15, b = gid >> 12;
    float off = 0.f;
    for (int j=0;j<ch;j++) off += part[((b*NCH + j)<<8) + c];
    const float* p = kf + ((size_t)b*NT + ch*NCL)*NC + c;
    float* o = sumk + ((size_t)b*NT + ch*NCL)*NC + c;
    float s = off;
    for (int i=0;i<NCL;i++){ s += p[(size_t)i*NC]; o[(size_t)i*NC] = s; }
}

// ---- wkv = Toeplitz @ kv, 128t x 64c tiles, fused epilogue -> bf16 swz ----
__global__ __launch_bounds__(256) void gemm_wkv(const unsigned short* __restrict__ Aexp,
                                                const unsigned short* __restrict__ kvt,
                                                const unsigned short* __restrict__ srb,
                                                const float* __restrict__ sumk,
                                                unsigned short* __restrict__ rout){
    __shared__ unsigned short As[2][128*64];   // 32KB
    __shared__ unsigned short Bs[2][64*64];    // 16KB
    const int tid = threadIdx.x;
    const int lane = tid & 63, w = tid >> 6;
    const int wm = (w >> 1) * 64, wn = (w & 1) * 32;   // wave tile 64x32
    const int lrow = lane & 15, kgrp = lane >> 4, lx = lane & 7;
    const int qrow = tid >> 3, qc = tid & 7;

    // pairing: blocks id and id+512 co-CU, workloads sum to 36 steps
    const int id = blockIdx.x;                 // 1024 blocks
    const int j = id & 511, hi = id >> 9;
    const int t_idx = hi ? 15 - (j >> 5) : (j >> 5);
    const int combo = (j & 31) | (hi << 5);    // 0..63
    const int b  = combo >> 2;
    const int c0 = (combo & 3) * 64;
    const int t0 = t_idx * 128;
    const int nsteps = 2*t_idx + 2;
    const unsigned short* Ab = Aexp + (size_t)(30 - 2*t_idx)*8192;

    f32x4 acc[4][2] = {};

    auto STAGE = [&](int buf, int s){
        const int u0 = s*64;
        #pragma unroll
        for (int i=0;i<4;i++){
            int row = qrow + 32*i;
            gload16(Ab + (size_t)s*8192 + (size_t)(row*8+qc)*8, &As[buf][(row*8+qc)*8]);
        }
        #pragma unroll
        for (int i=0;i<2;i++){
            int row = qrow + 32*i;
            gload16(kvt + ((size_t)(b*NC + c0 + row))*NT + u0 + qc*8, &Bs[buf][(row*8+qc)*8]);
        }
    };

    STAGE(0, 0);
    __syncthreads();
    for (int s = 0; s < nsteps; ++s){
        if (s+1 < nsteps) STAGE((s+1)&1, s+1);
        const unsigned short* as = As[s&1];
        const unsigned short* bs = Bs[s&1];
        #pragma unroll
        for (int ks = 0; ks < 2; ++ks){
            const int lk = ks*4 + kgrp;
            const int ch = (lk ^ lx) << 3;
            short8 a[4], b8[2];
            #pragma unroll
            for (int mi=0;mi<4;mi++) a[mi]  = *(const short8*)&as[(wm + mi*16 + lrow)*64 + ch];
            #pragma unroll
            for (int ni=0;ni<2;ni++) b8[ni] = *(const short8*)&bs[(wn + ni*16 + lrow)*64 + ch];
            #pragma unroll
            for (int mi=0;mi<4;mi++)
            #pragma unroll
            for (int ni=0;ni<2;ni++)
                acc[mi][ni] = __builtin_amdgcn_mfma_f32_16x16x32_bf16(a[mi], b8[ni], acc[mi][ni], 0,0,0);
        }
        __syncthreads();
    }

    const int orow = wm + kgrp*4;
    const int ocol = c0 + wn + lrow;
    #pragma unroll
    for (int mi=0;mi<4;mi++)
    #pragma unroll
    for (int ni=0;ni<2;ni++)
    #pragma unroll
    for (int i=0;i<4;i++){
        int t = t0 + orow + mi*16 + i;
        int col = ocol + ni*16;
        size_t g = (size_t)(b*NT + t)*NC + col;
        float sr = bf2f(srb[g]);
        float sk = sumk[g];
        float vv = sr * acc[mi][ni][i] / sk;
        int csw = (col & ~63) | ((((col>>3)&7) ^ (t&7)) << 3) | (col & 7);
        rout[(size_t)(b*NT + t)*NC + csw] = f2bf(vv);
    }
}

extern "C" void kernel_launch(void* const* d_in, const int* in_sizes, int n_in,
                              void* d_out, int out_size, void* d_ws, size_t ws_size,
                              hipStream_t stream) {
    const float* x   = (const float*)d_in[0];
    const float* tw  = (const float*)d_in[1];
    const float* tmk = (const float*)d_in[2];
    const float* tmv = (const float*)d_in[3];
    const float* tmr = (const float*)d_in[4];
    const float* Wk  = (const float*)d_in[5];
    const float* Wv  = (const float*)d_in[6];
    const float* Wr  = (const float*)d_in[7];
    const float* Wo  = (const float*)d_in[8];

    char* ws = (char*)d_ws;
    const size_t MC = (size_t)NM*NC;   // 8,388,608
    unsigned short* xk   = (unsigned short*)(ws);             // bf16 MC (swz)
    unsigned short* xv   = (unsigned short*)(ws + MC*2);      // bf16 MC (swz)
    unsigned short* xr   = (unsigned short*)(ws + MC*4);      // bf16 MC (swz)
    float*          kf   = (float*)(ws + MC*6);               // f32 MC
    unsigned short* vbT  = (unsigned short*)(ws + MC*10);     // bf16 MC, [B][C][T]
    unsigned short* srb  = (unsigned short*)(ws + MC*12);     // bf16 MC (sigmoid r)
    float*          sumk = (float*)(ws + MC*14);              // f32 MC
    unsigned short* kvt  = (unsigned short*)(ws + MC*18);     // bf16 MC (swz, [B][C][T])
    unsigned short* Aexp = (unsigned short*)(ws + MC*20);     // 512KB
    unsigned short* WkT  = (unsigned short*)(ws + MC*20 + 524288);
    unsigned short* WvT  = WkT + NC*NC;
    unsigned short* WrT  = WvT + NC*NC;
    unsigned short* WoT  = WrT + NC*NC;
    float*          part = (float*)(ws + MC*20 + 1048576);    // 256KB
    unsigned short* rwkvb = xk;   // xk dead after k-GEMM

    prep_kernel<<<256,256,0,stream>>>(tw, Wk,Wv,Wr,Wo, WkT,WvT,WrT,WoT, Aexp);
    mix_kernel<<<(int)(MC/8/256),256,0,stream>>>(x,tmk,tmv,tmr,xk,xv,xr);
    gemm_c<4><<<dim3(NM/128,NC/128),256,0,stream>>>(xv,WvT,vbT,nullptr,nullptr);
    gemm_c<5><<<dim3(NM/128,NC/128),256,0,stream>>>(xk,WkT,kf,vbT,kvt);
    gemm_c<3><<<dim3(NM/128,NC/128),256,0,stream>>>(xr,WrT,srb,nullptr,nullptr);
    scan1<<<256,256,0,stream>>>(kf,part);
    scan2<<<256,256,0,stream>>>(kf,part,sumk);
    gemm_wkv<<<1024,256,0,stream>>>(Aexp,kvt,srb,sumk,rwkvb);
    gemm_c<0><<<dim3(NM/128,NC/128),256,0,stream>>>(rwkvb,WoT,(float*)d_out,nullptr,nullptr);
}